// Round 15
// baseline (147.065 us; speedup 1.0000x reference)
//
#include <hip/hip_runtime.h>
#include <hip/hip_bf16.h>
#include <math.h>

#define TB 32
#define LOG2E 1.44269504f

typedef float f32x4 __attribute__((ext_vector_type(4)));
typedef _Float16 f16x8 __attribute__((ext_vector_type(8)));
typedef _Float16 f16x4 __attribute__((ext_vector_type(4)));
typedef _Float16 f16x2 __attribute__((ext_vector_type(2)));

// ---------------- ws layout (bytes), all weight mats f16 [col][k] -----------
#define OFF_W1T  344064
#define OFF_WOA  352256   // [64][64] = aWo^T
#define OFF_WOE  360448   // [64][64] = eWo^T
#define OFF_VBA  368640   // [64h][32k] = We@Wv fused (k=24 bias row)
#define OFF_VBE  372736
#define OFF_GA   376832   // [128][64]
#define OFF_GE   393216
#define OFF_GIH  409600
#define OFF_GHH  483328
#define OFF_GBS  507904
#define OFF_GBH  508672
#define OFF_BHD  508928

#define MFH(a, b, c) __builtin_amdgcn_mfma_f32_16x16x32_f16((a), (b), (c), 0, 0, 0)

__device__ inline float dot2(f16x2 a, f16x2 b, float c) {
#if __has_builtin(__builtin_amdgcn_fdot2)
  return __builtin_amdgcn_fdot2(a, b, c, false);
#else
  return c + (float)a[0] * (float)b[0] + (float)a[1] * (float)b[1];
#endif
}
__device__ inline f16x2 pk2(float x, float y) {
  f16x2 r; r[0] = (_Float16)x; r[1] = (_Float16)y; return r;
}

#define SV2(W, q) __builtin_shufflevector((W), (W), 2*(q), 2*(q)+1)

#define CVT12(Q0,Q1,Q2,Q3,Q4,Q5,R) \
  f16x2 R##_0=pk2(Q0.x,Q0.y), R##_1=pk2(Q0.z,Q0.w), \
        R##_2=pk2(Q1.x,Q1.y), R##_3=pk2(Q1.z,Q1.w), \
        R##_4=pk2(Q2.x,Q2.y), R##_5=pk2(Q2.z,Q2.w), \
        R##_6=pk2(Q3.x,Q3.y), R##_7=pk2(Q3.z,Q3.w), \
        R##_8=pk2(Q4.x,Q4.y), R##_9=pk2(Q4.z,Q4.w), \
        R##_10=pk2(Q5.x,Q5.y), R##_11=pk2(Q5.z,Q5.w)

#define ORV6(Q0,Q1,Q2,Q3,Q4,Q5) \
  ((Q0.x!=0.f)|(Q0.y!=0.f)|(Q0.z!=0.f)|(Q0.w!=0.f)| \
   (Q1.x!=0.f)|(Q1.y!=0.f)|(Q1.z!=0.f)|(Q1.w!=0.f)| \
   (Q2.x!=0.f)|(Q2.y!=0.f)|(Q2.z!=0.f)|(Q2.w!=0.f)| \
   (Q3.x!=0.f)|(Q3.y!=0.f)|(Q3.z!=0.f)|(Q3.w!=0.f)| \
   (Q4.x!=0.f)|(Q4.y!=0.f)|(Q4.z!=0.f)|(Q4.w!=0.f)| \
   (Q5.x!=0.f)|(Q5.y!=0.f)|(Q5.z!=0.f)|(Q5.w!=0.f))

#define DOT12(R, WA, WB, WC, BIAS) \
  dot2(R##_11, SV2(WC,3), dot2(R##_10, SV2(WC,2), dot2(R##_9, SV2(WC,1), dot2(R##_8, SV2(WC,0), \
  dot2(R##_7,  SV2(WB,3), dot2(R##_6,  SV2(WB,2), dot2(R##_5, SV2(WB,1), dot2(R##_4, SV2(WB,0), \
  dot2(R##_3,  SV2(WA,3), dot2(R##_2,  SV2(WA,2), dot2(R##_1, SV2(WA,1), dot2(R##_0, SV2(WA,0), \
  (BIAS)))))))))))))

// ============================================================= prep =========
__global__ __launch_bounds__(256)
void prep_kernel(const float* __restrict__ hyp_W1, const float* __restrict__ hyp_b1,
                 const float* __restrict__ hyp_W2, const float* __restrict__ hyp_b2,
                 const float* __restrict__ Wa, const float* __restrict__ ba,
                 const float* __restrict__ We, const float* __restrict__ be,
                 const float* __restrict__ aWq, const float* __restrict__ aWk,
                 const float* __restrict__ aWv, const float* __restrict__ aWo,
                 const float* __restrict__ eWq, const float* __restrict__ eWk,
                 const float* __restrict__ eWv, const float* __restrict__ eWo,
                 const float* __restrict__ gWih, const float* __restrict__ gWhh,
                 const float* __restrict__ gbih, const float* __restrict__ gbhh,
                 const float* __restrict__ WzK, const float* __restrict__ WEK,
                 const float* __restrict__ Wm,
                 void* __restrict__ ws)
{
  const int b = blockIdx.x, t = threadIdx.x;
  if (b < 42) {
    _Float16* o = (_Float16*)ws;
    for (int i = t; i < 4096; i += 256) {
      int h = i >> 6, k = i & 63;
      float v;
      if (b < 40)       v = hyp_W2[(size_t)k * 2628 + b * 64 + h];
      else if (b == 40) v = hyp_W2[(size_t)k * 2628 + 2560 + h];
      else              v = (k < 40) ? hyp_b2[k * 64 + h]
                             : (k == 40 ? hyp_b2[2560 + h] : 0.0f);
      o[b * 4096 + i] = (_Float16)v;
    }
  } else if (b == 42) {
    _Float16* o = (_Float16*)((char*)ws + OFF_W1T);
    for (int i = t; i < 4096; i += 256) {
      int h = i >> 6, k = i & 63;
      float v = (k < 40) ? hyp_W1[k * 64 + h] : (k == 40 ? hyp_b1[h] : 0.0f);
      o[i] = (_Float16)v;
    }
  } else if (b == 43 || b == 44) {
    const float* M = (b == 43) ? aWo : eWo;
    _Float16* o = (_Float16*)((char*)ws + (b == 43 ? OFF_WOA : OFF_WOE));
    for (int i = t; i < 4096; i += 256)
      o[i] = (_Float16)M[(i & 63) * 64 + (i >> 6)];
  } else if (b == 45 || b == 46) {
    const float* Wemb = (b == 45) ? Wa : We;
    const float* bemb = (b == 45) ? ba : be;
    const float* Wv   = (b == 45) ? aWv : eWv;
    _Float16* o = (_Float16*)((char*)ws + (b == 45 ? OFF_VBA : OFF_VBE));
    for (int i = t; i < 2048; i += 256) {
      int h = i >> 5, k = i & 31;
      float v = 0.f;
      if (k < 24)       { for (int d = 0; d < 64; ++d) v += Wemb[k * 64 + d] * Wv[d * 64 + h]; }
      else if (k == 24) { for (int d = 0; d < 64; ++d) v += bemb[d] * Wv[d * 64 + h]; }
      o[i] = (_Float16)v;
    }
  } else if (b == 47 || b == 48) {
    const float* Wemb = (b == 47) ? Wa : We;
    const float* bemb = (b == 47) ? ba : be;
    const float* Wk   = (b == 47) ? aWk : eWk;
    const float* Wq   = (b == 47) ? aWq : eWq;
    _Float16* o = (_Float16*)((char*)ws + (b == 47 ? OFF_GA : OFF_GE));
    __shared__ float sKb[25 * 64];
    for (int i = t; i < 1600; i += 256) {
      int k = i >> 6, c = i & 63;
      float v = 0.f;
      if (k < 24)  { for (int d = 0; d < 64; ++d) v += Wemb[k * 64 + d] * Wk[d * 64 + c]; }
      else         { for (int d = 0; d < 64; ++d) v += bemb[d] * Wk[d * 64 + c]; }
      sKb[i] = v;
    }
    __syncthreads();
    for (int i = t; i < 8192; i += 256) {
      int col = i >> 6, d = i & 63;
      int h = col >> 5, kk = col & 31;
      float v = 0.f;
      if (kk < 25)
        for (int dh = 0; dh < 16; ++dh)
          v += Wq[d * 64 + h * 16 + dh] * sKb[kk * 64 + h * 16 + dh];
      o[i] = (_Float16)(v * 0.25f * LOG2E);
    }
  } else if (b == 49) {
    _Float16* o = (_Float16*)((char*)ws + OFF_GIH);
    for (int i = t; i < 36864; i += 256) {
      int d = i / 192, c = i - d * 192;
      o[c * 192 + d] = (_Float16)gWih[i];
    }
  } else if (b == 50) {
    _Float16* o = (_Float16*)((char*)ws + OFF_GHH);
    for (int i = t; i < 12288; i += 256) {
      int d = i / 192, c = i - d * 192;
      o[c * 64 + d] = (_Float16)gWhh[i];
    }
  } else if (b == 51) {
    float* gbS = (float*)((char*)ws + OFF_GBS);
    float* gbH = (float*)((char*)ws + OFF_GBH);
    if (t < 192) gbS[t] = gbih[t] + (t < 128 ? gbhh[t] : 0.0f);
    if (t < 64)  gbH[t] = gbhh[128 + t];
  } else if (b == 52) { // head B-matrix
    __shared__ float sWsK[24 * 64];
    __shared__ float sbw[64];
    _Float16* o = (_Float16*)((char*)ws + OFF_BHD);
    for (int i = t; i < 1536; i += 256) {
      int j = i >> 6, h = i & 63;
      float v = 0.f;
      for (int c = 0; c < 64; ++c) v += We[j * 64 + c] * WEK[c * 64 + h];
      sWsK[i] = v;
    }
    if (t < 64) {
      float v = 0.f;
      for (int c = 0; c < 64; ++c) v += be[c] * WEK[c * 64 + t];
      sbw[t] = v;
    }
    __syncthreads();
    for (int i = t; i < 2048; i += 256) {
      int col = i >> 6, c = i & 63;
      float v = 0.f;
      if (col < 24)       { for (int d = 0; d < 64; ++d) v += WzK[c * 64 + d] * sWsK[col * 64 + d]; }
      else if (col == 24) { for (int d = 0; d < 64; ++d) v += WzK[c * 64 + d] * sbw[d]; }
      else if (col < 31)  v = Wm[c * 6 + (col - 25)];
      o[i] = (_Float16)v;
    }
  }
}

// ============================================================= main =========
__global__ __launch_bounds__(256, 4)
void agent_kernel(
    const float* __restrict__ own_raw, const float* __restrict__ ally_raw,
    const float* __restrict__ enemy_raw, const float* __restrict__ hidden,
    const float* __restrict__ bm,
    const void* __restrict__ ws,
    float* __restrict__ out, int BN)
{
  // LDS = 12800 (u16 [32][200]) + 25856 (R2 union) = 38656 B -> 4 blocks/CU
  __shared__ __align__(16) char s_all[38656];
  _Float16* s_u16 = (_Float16*)s_all;              // [32][200]
  char*     sR2   = s_all + 12800;
  // ph0-2 : own16 @0 [32][56]=3584 | ownT @3584 [40][32]=2560 | h116 @6144 [32][72]=4608
  // ph3   : w0 @0 [32][136]=8704 | w1 @8704 | pp0 @17408 [16][132]=4224 | pp1 @21632
  //         att0 alias w0 [32][72] | att1 alias w1 | hid16 @17408 [32][72] (3d, pp dead)
  // ph4+  : z16 @0 [32][72]=4608 | t16 @4608 [32][32] f16=2048 | q @17408 [32][22] f32
  _Float16* s_own16 = (_Float16*)sR2;
  _Float16* s_ownT  = (_Float16*)(sR2 + 3584);
  _Float16* s_h116  = (_Float16*)(sR2 + 6144);
  _Float16* s_w0    = (_Float16*)sR2;
  _Float16* s_w1    = (_Float16*)(sR2 + 8704);
  _Float16* s_pp0   = (_Float16*)(sR2 + 17408);
  _Float16* s_pp1   = (_Float16*)(sR2 + 21632);
  _Float16* s_att0  = (_Float16*)sR2;
  _Float16* s_att1  = (_Float16*)(sR2 + 8704);
  _Float16* s_hid16 = (_Float16*)(sR2 + 17408);
  _Float16* s_z16   = (_Float16*)sR2;
  _Float16* s_t16   = (_Float16*)(sR2 + 4608);
  float*    s_q     = (float*)(sR2 + 17408);

  const int tid = threadIdx.x;
  const int bs0 = blockIdx.x * TB;
  const int l   = tid & 63;
  const int wv  = tid >> 6;
  const int lr  = l & 15;
  const int oct = l >> 4;
  const int s8  = tid >> 3;
  const int sh  = tid & 7;

  const f16x8 ZERO8F = {0,0,0,0,0,0,0,0};
  f16x8 ONE8F = ZERO8F; ONE8F[0] = (_Float16)1.0f;
  const f32x4 ZERO4 = {0.f, 0.f, 0.f, 0.f};

  // ---------------- phase 0: stage own (f16 + f16-T) ----------------
  for (int i = tid; i < 640; i += 256) {
    int ss = i / 20, c = i - ss * 20;
    float2 v = *(const float2*)(own_raw + (size_t)(bs0 + ss) * 40 + c * 2);
    *(f16x2*)(s_own16 + ss * 56 + c * 2) = pk2(v.x, v.y);
  }
  for (int i = tid; i < 1280; i += 256) {
    int f = i >> 5, s2 = i & 31;
    s_ownT[i] = (_Float16)own_raw[(size_t)(bs0 + s2) * 40 + f];
  }
  __syncthreads();

  // ---------------- phase 1: h1 = relu(own @ W1 + b1), 2 row-tiles ---------
  {
    const _Float16* w1t = (const _Float16*)((const char*)ws + OFF_W1T);
    f16x8 b0 = *(const f16x8*)(w1t + (wv * 16 + lr) * 64 + oct * 8);
    f16x8 b1 = *(const f16x8*)(w1t + (wv * 16 + lr) * 64 + 32 + oct * 8);
    #pragma unroll
    for (int rt = 0; rt < 2; ++rt) {
      f16x8 a0 = *(const f16x8*)(s_own16 + (rt * 16 + lr) * 56 + oct * 8);
      f16x8 a1;
      if (oct == 0)      a1 = *(const f16x8*)(s_own16 + (rt * 16 + lr) * 56 + 32);
      else if (oct == 1) a1 = ONE8F;
      else               a1 = ZERO8F;
      f32x4 acc = ZERO4;
      acc = MFH(a0, b0, acc);
      acc = MFH(a1, b1, acc);
      #pragma unroll
      for (int j = 0; j < 4; ++j)
        s_h116[(rt * 16 + oct * 4 + j) * 72 + wv * 16 + lr] = (_Float16)fmaxf(acc[j], 0.f);
    }
  }
  __syncthreads();

  // ---------------- phase 2: own_e, scale-in-acc, 2 row-tiles, shared B ----
  {
    const _Float16* bb = (const _Float16*)ws + (size_t)(wv * 16 + lr) * 64 + oct * 8;
    f16x8 h0f0 = *(const f16x8*)(s_h116 + lr * 72 + oct * 8);
    f16x8 h1f0 = *(const f16x8*)(s_h116 + lr * 72 + 32 + oct * 8);
    f16x8 h0f1 = *(const f16x8*)(s_h116 + (16 + lr) * 72 + oct * 8);
    f16x8 h1f1 = *(const f16x8*)(s_h116 + (16 + lr) * 72 + 32 + oct * 8);
    f32x4 acc0 = ZERO4, acc1 = ZERO4;
    #pragma unroll 4
    for (int f = 0; f < 40; ++f) {
      f16x8 b0 = *(const f16x8*)(bb + (size_t)f * 4096);
      f16x8 b1 = *(const f16x8*)(bb + (size_t)f * 4096 + 32);
      f32x4 y0 = MFH(h0f0, b0, ZERO4); y0 = MFH(h1f0, b1, y0);
      f32x4 y1 = MFH(h0f1, b0, ZERO4); y1 = MFH(h1f1, b1, y1);
      f16x4 ov0 = *(const f16x4*)(s_ownT + f * 32 + oct * 4);
      f16x4 ov1 = *(const f16x4*)(s_ownT + f * 32 + 16 + oct * 4);
      #pragma unroll
      for (int j = 0; j < 4; ++j) {
        acc0[j] += (float)ov0[j] * y0[j];
        acc1[j] += (float)ov1[j] * y1[j];
      }
    }
    f32x4 aD0 = ZERO4, aD1 = ZERO4;
    {
      f16x8 b0 = *(const f16x8*)(bb + (size_t)40 * 4096);
      f16x8 b1 = *(const f16x8*)(bb + (size_t)40 * 4096 + 32);
      aD0 = MFH(h0f0, b0, aD0); aD0 = MFH(h1f0, b1, aD0);
      aD1 = MFH(h0f1, b0, aD1); aD1 = MFH(h1f1, b1, aD1);
    }
    {
      f16x8 b0 = *(const f16x8*)(bb + (size_t)41 * 4096);
      f16x8 b1 = *(const f16x8*)(bb + (size_t)41 * 4096 + 32);
      #pragma unroll
      for (int rt = 0; rt < 2; ++rt) {
        f16x8 a0 = *(const f16x8*)(s_own16 + (rt * 16 + lr) * 56 + oct * 8);
        f16x8 a1;
        if (oct == 0)      a1 = *(const f16x8*)(s_own16 + (rt * 16 + lr) * 56 + 32);
        else if (oct == 1) a1 = ONE8F;
        else               a1 = ZERO8F;
        if (rt) { aD1 = MFH(a0, b0, aD1); aD1 = MFH(a1, b1, aD1); }
        else    { aD0 = MFH(a0, b0, aD0); aD0 = MFH(a1, b1, aD0); }
      }
    }
    #pragma unroll
    for (int j = 0; j < 4; ++j) {
      s_u16[(oct * 4 + j) * 200 + wv * 16 + lr]      = (_Float16)(acc0[j] + aD0[j]);
      s_u16[(16 + oct * 4 + j) * 200 + wv * 16 + lr] = (_Float16)(acc1[j] + aD1[j]);
    }
  }
  __syncthreads();

  // ---------------- phase 3a: w = own_e @ G, BOTH sides --------------------
  {
    f16x8 a00 = *(const f16x8*)(s_u16 + lr * 200 + oct * 8);
    f16x8 a10 = *(const f16x8*)(s_u16 + lr * 200 + 32 + oct * 8);
    f16x8 a01 = *(const f16x8*)(s_u16 + (16 + lr) * 200 + oct * 8);
    f16x8 a11 = *(const f16x8*)(s_u16 + (16 + lr) * 200 + 32 + oct * 8);
    #pragma unroll
    for (int side = 0; side < 2; ++side) {
      const _Float16* gT = (const _Float16*)((const char*)ws + (side ? OFF_GE : OFF_GA));
      _Float16* wDst = side ? s_w1 : s_w0;
      #pragma unroll
      for (int t2 = 0; t2 < 2; ++t2) {
        int col = wv * 32 + t2 * 16 + lr;
        f16x8 b0 = *(const f16x8*)(gT + col * 64 + oct * 8);
        f16x8 b1 = *(const f16x8*)(gT + col * 64 + 32 + oct * 8);
        f32x4 ac0 = ZERO4, ac1 = ZERO4;
        ac0 = MFH(a00, b0, ac0); ac0 = MFH(a10, b1, ac0);
        ac1 = MFH(a01, b0, ac1); ac1 = MFH(a11, b1, ac1);
        #pragma unroll
        for (int j = 0; j < 4; ++j) {
          wDst[(oct * 4 + j) * 136 + col]      = (_Float16)ac0[j];
          wDst[(16 + oct * 4 + j) * 136 + col] = (_Float16)ac1[j];
        }
      }
    }
  }
  __syncthreads();

  // ---------------- phase 3b: score BOTH sides (reg w-row, fdot2) ----------
  {
    #pragma unroll
    for (int side = 0; side < 2; ++side) {
      const int n_ent = side ? 16 : 15;
      const int rstr  = side ? 384 : 360;
      const float* rawg = side ? enemy_raw : ally_raw;
      const _Float16* wp = (side ? s_w1 : s_w0) + s8 * 136;
      _Float16* pp = side ? s_pp1 : s_pp0;

      const int n1 = (sh + 8 < n_ent) ? (sh + 8) : 0;
      const float* rp0 = rawg + (size_t)(bs0 + s8) * rstr + sh * 24;
      const float* rp1 = rawg + (size_t)(bs0 + s8) * rstr + n1 * 24;
      float4 qa0 = *(const float4*)(rp0);      float4 qa1 = *(const float4*)(rp0 + 4);
      float4 qa2 = *(const float4*)(rp0 + 8);  float4 qa3 = *(const float4*)(rp0 + 12);
      float4 qa4 = *(const float4*)(rp0 + 16); float4 qa5 = *(const float4*)(rp0 + 20);
      float4 qb0 = *(const float4*)(rp1);      float4 qb1 = *(const float4*)(rp1 + 4);
      float4 qb2 = *(const float4*)(rp1 + 8);  float4 qb3 = *(const float4*)(rp1 + 12);
      float4 qb4 = *(const float4*)(rp1 + 16); float4 qb5 = *(const float4*)(rp1 + 20);
      unsigned oa = ORV6(qa0, qa1, qa2, qa3, qa4, qa5);
      unsigned ob = ORV6(qb0, qb1, qb2, qb3, qb4, qb5);
      CVT12(qa0, qa1, qa2, qa3, qa4, qa5, ra);
      // w-row registers (shared across both entity rows)
      f16x8 w0a = *(const f16x8*)(wp +  0), w0b = *(const f16x8*)(wp +  8), w0c = *(const f16x8*)(wp + 16);
      f16x8 w1a = *(const f16x8*)(wp + 32), w1b = *(const f16x8*)(wp + 40), w1c = *(const f16x8*)(wp + 48);
      f16x8 w2a = *(const f16x8*)(wp + 64), w2b = *(const f16x8*)(wp + 72), w2c = *(const f16x8*)(wp + 80);
      f16x8 w3a = *(const f16x8*)(wp + 96), w3b = *(const f16x8*)(wp +104), w3c = *(const f16x8*)(wp +112);
      float bi0 = (float)wp[24], bi1 = (float)wp[56], bi2 = (float)wp[88], bi3 = (float)wp[120];

      f32x4 sc0, sc1;
      sc0[0] = oa ? DOT12(ra, w0a, w0b, w0c, bi0) : -1.0e9f;
      sc0[1] = oa ? DOT12(ra, w1a, w1b, w1c, bi1) : -1.0e9f;
      sc0[2] = oa ? DOT12(ra, w2a, w2b, w2c, bi2) : -1.0e9f;
      sc0[3] = oa ? DOT12(ra, w3a, w3b, w3c, bi3) : -1.0e9f;
      CVT12(qb0, qb1, qb2, qb3, qb4, qb5, rb);
      sc1[0] = ob ? DOT12(rb, w0a, w0b, w0c, bi0) : -1.0e9f;
      sc1[1] = ob ? DOT12(rb, w1a, w1b, w1c, bi1) : -1.0e9f;
      sc1[2] = ob ? DOT12(rb, w2a, w2b, w2c, bi2) : -1.0e9f;
      sc1[3] = ob ? DOT12(rb, w3a, w3b, w3c, bi3) : -1.0e9f;
      if (sh + 8 >= n_ent) {
        #pragma unroll
        for (int h = 0; h < 4; ++h) sc1[h] = -2.0e9f;
      }
      f32x4 m, lsum, p0v, p1v;
      #pragma unroll
      for (int h = 0; h < 4; ++h) m[h] = fmaxf(sc0[h], sc1[h]);
      #pragma unroll
      for (int d = 1; d < 8; d <<= 1) {
        #pragma unroll
        for (int h = 0; h < 4; ++h) m[h] = fmaxf(m[h], __shfl_xor(m[h], d));
      }
      #pragma unroll
      for (int h = 0; h < 4; ++h) {
        p0v[h] = __builtin_exp2f(sc0[h] - m[h]);
        p1v[h] = __builtin_exp2f(sc1[h] - m[h]);
        lsum[h] = p0v[h] + p1v[h];
      }
      #pragma unroll
      for (int d = 1; d < 8; d <<= 1) {
        #pragma unroll
        for (int h = 0; h < 4; ++h) lsum[h] += __shfl_xor(lsum[h], d);
      }
      f32x4 rl;
      #pragma unroll
      for (int h = 0; h < 4; ++h) rl[h] = __builtin_amdgcn_rcpf(lsum[h]);
      {
        f16x4 pk;
        #pragma unroll
        for (int h = 0; h < 4; ++h) pk[h] = (_Float16)(p0v[h] * rl[h]);
        *(f16x4*)(pp + sh * 132 + s8 * 4) = pk;
      }
      {
        f16x4 pk;   // phantom rows store exp2(-huge)=0 naturally
        #pragma unroll
        for (int h = 0; h < 4; ++h) pk[h] = (_Float16)(p1v[h] * rl[h]);
        *(f16x4*)(pp + (sh + 8) * 132 + s8 * 4) = pk;
      }
    }
  }
  __syncthreads();

  // ---------------- phase 3c: PV BOTH sides (fixed 16-iter, f32-mul frags) -
  {
    #pragma unroll
    for (int side = 0; side < 2; ++side) {
      const int n_ent = side ? 16 : 15;
      const int rstr  = side ? 384 : 360;
      const float* rawg = side ? enemy_raw : ally_raw;
      const _Float16* vbT = (const _Float16*)((const char*)ws + (side ? OFF_VBE : OFF_VBA));
      const _Float16* pp = side ? s_pp1 : s_pp0;
      _Float16* attD = side ? s_att1 : s_att0;

      f16x8 vbF = *(const f16x8*)(vbT + (wv * 16 + lr) * 32 + oct * 8);
      const float* rpv0 = rawg + (size_t)(bs0 + lr) * rstr + oct * 8;
      const float* rpv1 = rawg + (size_t)(bs0 + 16 + lr) * rstr + oct * 8;
      f32x4 oac0 = ZERO4, oac1 = ZERO4;
      #pragma unroll
      for (int i = 0; i < 16; ++i) {
        const int ii = (i < n_ent) ? i : 0;      // compile-time per side
        float pwf0 = (float)pp[i * 132 + lr * 4 + wv];
        float pwf1 = (float)pp[i * 132 + (16 + lr) * 4 + wv];
        f16x8 fr0, fr1;
        if (oct < 3) {
          float4 a = *(const float4*)(rpv0 + ii * 24);
          float4 b = *(const float4*)(rpv0 + ii * 24 + 4);
          f16x4 lo0 = __builtin_shufflevector(pk2(a.x*pwf0, a.y*pwf0), pk2(a.z*pwf0, a.w*pwf0), 0,1,2,3);
          f16x4 hi0 = __builtin_shufflevector(pk2(b.x*pwf0, b.y*pwf0), pk2(b.z*pwf0, b.w*pwf0), 0,1,2,3);
          fr0 = __builtin_shufflevector(lo0, hi0, 0,1,2,3,4,5,6,7);
          float4 c = *(const float4*)(rpv1 + ii * 24);
          float4 d = *(const float4*)(rpv1 + ii * 24 + 4);
          f16x4 lo1 = __builtin_shufflevector(pk2(c.x*pwf1, c.y*pwf1), pk2(c.z*pwf1, c.w*pwf1), 0,1,2,3);
          f16x4 hi1 = __builtin_shufflevector(pk2(d.x*pwf1, d.y*pwf1), pk2(d.z*pwf1, d.w*pwf1), 0,1,2,3);
          fr1 = __builtin_shufflevector(lo1, hi1, 0,1,2,3,4,5,6,7);
        } else {
          fr0 = ZERO8F; fr0[0] = (_Float16)pwf0;
          fr1 = ZERO8F; fr1[0] = (_Float16)pwf1;
        }
        oac0 = MFH(fr0, vbF, oac0);
        oac1 = MFH(fr1, vbF, oac1);
      }
      #pragma unroll
      for (int j = 0; j < 4; ++j) {
        attD[(oct * 4 + j) * 72 + wv * 16 + lr]      = (_Float16)oac0[j];
        attD[(16 + oct * 4 + j) * 72 + wv * 16 + lr] = (_Float16)oac1[j];
      }
    }
  }
  __syncthreads();

  // ---------------- phase 3d: o-GEMM BOTH sides + stage hidden -------------
  {
    #pragma unroll
    for (int side = 0; side < 2; ++side) {
      const _Float16* woT = (const _Float16*)((const char*)ws + (side ? OFF_WOE : OFF_WOA));
      const _Float16* attS = side ? s_att1 : s_att0;
      f16x8 b0 = *(const f16x8*)(woT + (wv * 16 + lr) * 64 + oct * 8);
      f16x8 b1 = *(const f16x8*)(woT + (wv * 16 + lr) * 64 + 32 + oct * 8);
      #pragma unroll
      for (int rt = 0; rt < 2; ++rt) {
        f16x8 a0 = *(const f16x8*)(attS + (rt * 16 + lr) * 72 + oct * 8);
        f16x8 a1 = *(const f16x8*)(attS + (rt * 16 + lr) * 72 + 32 + oct * 8);
        f32x4 oa = ZERO4;
        oa = MFH(a0, b0, oa);
        oa = MFH(a1, b1, oa);
        #pragma unroll
        for (int j = 0; j < 4; ++j)
          s_u16[(rt * 16 + oct * 4 + j) * 200 + 64 + side * 64 + wv * 16 + lr] = (_Float16)oa[j];
      }
    }
    for (int i = tid; i < 1024; i += 256) {
      int ss = i >> 5, c = i & 31;
      float2 v = *(const float2*)(hidden + (size_t)(bs0 + ss) * 64 + c * 2);
      *(f16x2*)(s_hid16 + ss * 72 + c * 2) = pk2(v.x, v.y);
    }
  }
  __syncthreads();

  // ---------------- phase 4: GRU (f16 MFMA, 2 row-tiles, shared B) ---------
  {
    const _Float16* ihT = (const _Float16*)((const char*)ws + OFF_GIH);
    const _Float16* hhT = (const _Float16*)((const char*)ws + OFF_GHH);
    const float* gbS = (const float*)((const char*)ws + OFF_GBS);
    const float* gbH = (const float*)((const char*)ws + OFF_GBH);
    f32x4 aX0[2] = {ZERO4, ZERO4}, aX1[2] = {ZERO4, ZERO4};
    f32x4 aX2[2] = {ZERO4, ZERO4}, aH2[2] = {ZERO4, ZERO4};
    #pragma unroll
    for (int st = 0; st < 6; ++st) {
      f16x8 uf0 = *(const f16x8*)(s_u16 + lr * 200 + st * 32 + oct * 8);
      f16x8 uf1 = *(const f16x8*)(s_u16 + (16 + lr) * 200 + st * 32 + oct * 8);
      f16x8 b0 = *(const f16x8*)(ihT + ((wv    ) * 16 + lr) * 192 + st * 32 + oct * 8);
      f16x8 b1 = *(const f16x8*)(ihT + ((wv + 4) * 16 + lr) * 192 + st * 32 + oct * 8);
      f16x8 b2 = *(const f16x8*)(ihT + ((wv + 8) * 16 + lr) * 192 + st * 32 + oct * 8);
      aX0[0] = MFH(uf0, b0, aX0[0]);  aX0[1] = MFH(uf1, b0, aX0[1]);
      aX1[0] = MFH(uf0, b1, aX1[0]);  aX1[1] = MFH(uf1, b1, aX1[1]);
      aX2[0] = MFH(uf0, b2, aX2[0]);  aX2[1] = MFH(uf1, b2, aX2[1]);
    }
    #pragma unroll
    for (int st = 0; st < 2; ++st) {
      f16x8 hf0 = *(const f16x8*)(s_hid16 + lr * 72 + st * 32 + oct * 8);
      f16x8 hf1 = *(const f16x8*)(s_hid16 + (16 + lr) * 72 + st * 32 + oct * 8);
      f16x8 b0 = *(const f16x8*)(hhT + ((wv    ) * 16 + lr) * 64 + st * 32 + oct * 8);
      f16x8 b1 = *(const f16x8*)(hhT + ((wv + 4) * 16 + lr) * 64 + st * 32 + oct * 8);
      f16x8 b2 = *(const f16x8*)(hhT + ((wv + 8) * 16 + lr) * 64 + st * 32 + oct * 8);
      aX0[0] = MFH(hf0, b0, aX0[0]);  aX0[1] = MFH(hf1, b0, aX0[1]);
      aX1[0] = MFH(hf0, b1, aX1[0]);  aX1[1] = MFH(hf1, b1, aX1[1]);
      aH2[0] = MFH(hf0, b2, aH2[0]);  aH2[1] = MFH(hf1, b2, aH2[1]);
    }
    const int c0 = wv * 16 + lr;
    float bb0 = gbS[c0], bb1 = gbS[c0 + 64], bb2 = gbS[c0 + 128], bbh = gbH[c0];
    __syncthreads();   // all s_u16/att reads done before z16 overwrites R2
    #pragma unroll
    for (int rt = 0; rt < 2; ++rt) {
      #pragma unroll
      for (int j = 0; j < 4; ++j) {
        int row = rt * 16 + oct * 4 + j;
        float xr = aX0[rt][j] + bb0;
        float xz = aX1[rt][j] + bb1;
        float xn = aX2[rt][j] + bb2;
        float hn = aH2[rt][j] + bbh;
        float r  = __builtin_amdgcn_rcpf(1.f + __builtin_exp2f(-xr * LOG2E));
        float zg = __builtin_amdgcn_rcpf(1.f + __builtin_exp2f(-xz * LOG2E));
        float ta = xn + r * hn;
        float nc = 1.f - 2.f * __builtin_amdgcn_rcpf(1.f + __builtin_exp2f(2.f * LOG2E * ta));
        float hv = (float)s_hid16[row * 72 + c0];
        s_z16[row * 72 + c0] = (_Float16)((1.f - zg) * nc + zg * hv);
      }
    }
  }
  __syncthreads();

  // ---------------- phase 5: fused head GEMM (all 4 waves) -----------------
  {
    const _Float16* bhT = (const _Float16*)((const char*)ws + OFF_BHD);
    const int rt = wv >> 1;
    const int col = (wv & 1) * 16 + lr;
    f16x8 a0 = *(const f16x8*)(s_z16 + (rt * 16 + lr) * 72 + oct * 8);
    f16x8 a1 = *(const f16x8*)(s_z16 + (rt * 16 + lr) * 72 + 32 + oct * 8);
    f16x8 b0 = *(const f16x8*)(bhT + col * 64 + oct * 8);
    f16x8 b1 = *(const f16x8*)(bhT + col * 64 + 32 + oct * 8);
    f32x4 td = ZERO4;
    td = MFH(a0, b0, td);
    td = MFH(a1, b1, td);
    #pragma unroll
    for (int j = 0; j < 4; ++j) {
      int row = rt * 16 + oct * 4 + j;
      if (col < 25)      s_t16[row * 32 + col] = (_Float16)td[j];
      else if (col < 31) s_q[row * 22 + (col - 25)] = td[j] + bm[col - 25];
    }
  }
  __syncthreads();
  // shoot logits: thread (s8, entities sh & sh+8), t-row in registers
  {
    const _Float16* tp = s_t16 + s8 * 32;
    f16x8 t0 = *(const f16x8*)(tp);
    f16x8 t1 = *(const f16x8*)(tp + 8);
    f16x8 t2 = *(const f16x8*)(tp + 16);
    float c24 = (float)tp[24];
    #pragma unroll
    for (int e = 0; e < 2; ++e) {
      int m = sh + e * 8;
      const float* er = enemy_raw + (size_t)(bs0 + s8) * 384 + m * 24;
      float4 q0 = *(const float4*)(er);      float4 q1 = *(const float4*)(er + 4);
      float4 q2 = *(const float4*)(er + 8);  float4 q3 = *(const float4*)(er + 12);
      float4 q4 = *(const float4*)(er + 16); float4 q5 = *(const float4*)(er + 20);
      CVT12(q0, q1, q2, q3, q4, q5, rs);
      s_q[s8 * 22 + 6 + m] = DOT12(rs, t0, t1, t2, c24);
    }
  }
  __syncthreads();
  // coalesced output tail
  for (int i = tid; i < 704; i += 256)
    out[(size_t)bs0 * 22 + i] = s_q[i];
  for (int i = tid; i < 2048; i += 256)
    out[(size_t)BN * 22 + (size_t)bs0 * 64 + i] = (float)s_z16[(i >> 6) * 72 + (i & 63)];
}

// ============================================================= launch =======
extern "C" void kernel_launch(void* const* d_in, const int* in_sizes, int n_in,
                              void* d_out, int out_size, void* d_ws, size_t ws_size,
                              hipStream_t stream) {
  (void)n_in; (void)out_size; (void)ws_size;
  const float* own_raw   = (const float*)d_in[0];
  const float* ally_raw  = (const float*)d_in[1];
  const float* enemy_raw = (const float*)d_in[2];
  const float* hidden    = (const float*)d_in[3];
  const float* hyp_W1    = (const float*)d_in[4];
  const float* hyp_b1    = (const float*)d_in[5];
  const float* hyp_W2    = (const float*)d_in[6];
  const float* hyp_b2    = (const float*)d_in[7];
  const float* Wa        = (const float*)d_in[8];
  const float* ba        = (const float*)d_in[9];
  const float* We        = (const float*)d_in[10];
  const float* be        = (const float*)d_in[11];
  const float* aWq       = (const float*)d_in[12];
  const float* aWk       = (const float*)d_in[13];
  const float* aWv       = (const float*)d_in[14];
  const float* aWo       = (const float*)d_in[15];
  const float* eWq       = (const float*)d_in[16];
  const float* eWk       = (const float*)d_in[17];
  const float* eWv       = (const float*)d_in[18];
  const float* eWo       = (const float*)d_in[19];
  const float* gWih      = (const float*)d_in[20];
  const float* gWhh      = (const float*)d_in[21];
  const float* gbih      = (const float*)d_in[22];
  const float* gbhh      = (const float*)d_in[23];
  const float* Wm        = (const float*)d_in[24];
  const float* bm        = (const float*)d_in[25];
  const float* WzK       = (const float*)d_in[26];
  const float* WEK       = (const float*)d_in[27];
  int BN = in_sizes[0] / 40;
  int blocks = BN / TB;

  hipLaunchKernelGGL(prep_kernel, dim3(53), dim3(256), 0, stream,
                     hyp_W1, hyp_b1, hyp_W2, hyp_b2, Wa, ba, We, be,
                     aWq, aWk, aWv, aWo, eWq, eWk, eWv, eWo,
                     gWih, gWhh, gbih, gbhh, WzK, WEK, Wm, d_ws);
  hipLaunchKernelGGL(agent_kernel, dim3(blocks), dim3(256), 0, stream,
                     own_raw, ally_raw, enemy_raw, hidden, bm,
                     d_ws, (float*)d_out, BN);
}